// Round 11
// baseline (1929.284 us; speedup 1.0000x reference)
//
#include <hip/hip_runtime.h>

#define PTOT  16384
#define CCC   512
#define HHH   8
#define NK1   32                 /* k1: 512/16 k-steps */
#define NK2   16                 /* k2: 512/32 k-steps */

typedef __attribute__((ext_vector_type(4)))  float f32x4;
typedef __attribute__((ext_vector_type(16))) float f32x16;
typedef _Float16 half_t;
typedef __attribute__((ext_vector_type(8))) _Float16 f16x8;

#define MFMA16(a,b,c) __builtin_amdgcn_mfma_f32_16x16x32_f16(a,b,c,0,0,0)
#define MFMA32(a,b,c) __builtin_amdgcn_mfma_f32_32x32x16_f16(a,b,c,0,0,0)

// ---- ws plane layout (half elements) ----
#define XH_OFF   ((size_t)0)
#define XL_OFF   ((size_t)33554432)
#define ACT_OFF  ((size_t)67108864)
#define W_OFF    ((size_t)100663296)
#define WPL      ((size_t)262144)
// W plane order: 0 qh, 1 ql, 2 kh, 3 kl, 4 vh, 5 oh

#define SCB()   __builtin_amdgcn_sched_barrier(0)
#define SBAR()  __builtin_amdgcn_s_barrier()

// 16-row frag layout (act plane + Wo plane; k2 consumes via 16x16x32 MFMA)
__device__ __forceinline__ size_t blk_off16(int row, int col) {
    return ((size_t)((row >> 4) * 16 + (col >> 5)) << 9)
         + (size_t)(((((col >> 3) & 3) * 16) + (row & 15)) << 3) + (col & 7);
}

// ---------------------------------------------------------------------------
// k0: split fp32 -> fp16 hi/lo planes (unchanged).
// ---------------------------------------------------------------------------
__global__ void k0_split(const float* __restrict__ x,
                         const float* __restrict__ Wq, const float* __restrict__ Wk,
                         const float* __restrict__ Wv, const float* __restrict__ Wo,
                         half_t* __restrict__ ws)
{
    const int u = blockIdx.x * 256 + threadIdx.x;   // 4,325,376 threads
    if (u < 4194304) {                              // ---- x region ----
        const int f = u >> 6, lane6 = u & 63;
        const int grow32 = f >> 5, ktc = f & 31;
        const int row = grow32 * 32 + (lane6 & 31);
        const int k   = ktc * 16 + (lane6 >> 5) * 8;
        const float4 a = *(const float4*)(x + (size_t)row * CCC + k);
        const float4 b = *(const float4*)(x + (size_t)row * CCC + k + 4);
        const float e[8] = {a.x, a.y, a.z, a.w, b.x, b.y, b.z, b.w};
        f16x8 vh8, vl8;
        #pragma unroll
        for (int d = 0; d < 8; ++d) {
            const half_t hi = (half_t)e[d];
            vh8[d] = hi; vl8[d] = (half_t)(e[d] - (float)hi);
        }
        const size_t off = ((size_t)f << 9) + lane6 * 8;
        *(f16x8*)(ws + XH_OFF + off) = vh8;
        *(f16x8*)(ws + XL_OFF + off) = vl8;
        return;
    }
    const int u2  = u - 4194304;
    const int mat = u2 >> 15, r = u2 & 32767;
    if (mat < 3) {                                  // ---- Wq/Wk/Wv, 32-layout ----
        const float* src = (mat == 0) ? Wq : (mat == 1) ? Wk : Wv;
        const int f = r >> 6, lane6 = r & 63;
        const int grow32 = f >> 5, ktc = f & 31;
        const int row = grow32 * 32 + (lane6 & 31);
        const int k   = ktc * 16 + (lane6 >> 5) * 8;
        const float4 a = *(const float4*)(src + (size_t)row * CCC + k);
        const float4 b = *(const float4*)(src + (size_t)row * CCC + k + 4);
        const float e[8] = {a.x, a.y, a.z, a.w, b.x, b.y, b.z, b.w};
        f16x8 vh8, vl8;
        #pragma unroll
        for (int d = 0; d < 8; ++d) {
            const half_t hi = (half_t)e[d];
            vh8[d] = hi; vl8[d] = (half_t)(e[d] - (float)hi);
        }
        const size_t off = ((size_t)f << 9) + lane6 * 8;
        half_t* dh = ws + W_OFF + (size_t)(mat * 2) * WPL;
        *(f16x8*)(dh + off) = vh8;
        if (mat < 2) *(f16x8*)(dh + WPL + off) = vl8;   // lo plane for q,k only
        return;
    }
    // ---- Wo, 16-layout ----
    const int gr = r >> 10, v = r & 1023;
    const int ktc = v >> 6, chunk = (v >> 4) & 3, i = v & 15;
    const int row = gr * 16 + i, col = ktc * 32 + chunk * 8;
    const float4 a = *(const float4*)(Wo + (size_t)row * CCC + col);
    const float4 b = *(const float4*)(Wo + (size_t)row * CCC + col + 4);
    const float e[8] = {a.x, a.y, a.z, a.w, b.x, b.y, b.z, b.w};
    f16x8 vh8;
    #pragma unroll
    for (int d = 0; d < 8; ++d) vh8[d] = (half_t)e[d];
    *(f16x8*)(ws + W_OFF + 5 * WPL + blk_off16(row, col)) = vh8;
}

// ---------------------------------------------------------------------------
// k1: QKV projection via fp16x2 32x32x16 MFMA (Q:3,K:3,V:1) + spiking attn.
// r5-proven K-loop (counted vmcnt, 2 barriers/kt). LDS shrunk to 36,864B
// (epilogue uses qa/ka + v-overlay) -> 4 blocks/CU = 16 waves/CU.
// ---------------------------------------------------------------------------
__global__ __launch_bounds__(256, 4)
void k1_mfma(const half_t* __restrict__ ws,
             const float* __restrict__ bq, const float* __restrict__ bk,
             const float* __restrict__ bv,
             half_t* __restrict__ acth)
{
    __shared__ __align__(16) char smem[36864];

    const int tid  = threadIdx.x;
    const int lane = tid & 63;
    const int wv   = tid >> 6;
    const int rg   = wv >> 1;        // row half: 64 rows
    const int cg   = wv & 1;         // col half: 32 cols
    const int l31  = lane & 31;
    const int l5   = lane >> 5;

    const int xcd  = blockIdx.x & 7;
    const int rest = blockIdx.x >> 3;
    const int h    = rest & 7;
    const int tg   = rest >> 3;
    const int p0   = (tg * 8 + xcd) * 32;

    // ---- staging issue list: 18 frags/kt/block, waves get [5,5,4,4] ----
    const int cnt  = (wv < 2) ? 5 : 4;
    const int base = (wv < 2) ? wv * 5 : 2 + wv * 4;
    const half_t* gb[5]; int lo_[5];
    #pragma unroll
    for (int ii = 0; ii < 5; ++ii) {
        const int i = base + ii;
        size_t eoff; int loff;
        if (i < 8) {            // X frag: t = i>>1, plane = i&1
            const int t = i >> 1, pl = i & 1;
            const size_t rbg = (size_t)t * 512 + (p0 >> 5);
            eoff = (pl ? XL_OFF : XH_OFF) + (rbg << 14) + lane * 8;
            loff = i * 1024;
        } else {                // W frag: s = i-8: plane = s>>1, cb = s&1
            const int s = (i - 8) & 15;
            const int plw = (s >> 1) > 4 ? 4 : (s >> 1), cb = s & 1;
            eoff = W_OFF + (size_t)plw * WPL + ((size_t)(h * 2 + cb) << 14) + lane * 8;
            loff = 8192 + s * 1024;
        }
        gb[ii] = ws + eoff;
        lo_[ii] = loff;
    }

#define K1_STAGE(buf, kt) do {                                                  \
    _Pragma("unroll")                                                           \
    for (int ii = 0; ii < 5; ++ii)                                              \
        if (ii < cnt)                                                           \
            __builtin_amdgcn_global_load_lds(                                   \
                (const __attribute__((address_space(1))) void*)(gb[ii] + (size_t)(kt) * 512), \
                (__attribute__((address_space(3))) void*)(smem + (buf) * 18432 + lo_[ii]),    \
                16, 0, 0);                                                      \
    } while (0)

    // ---- accumulators (bias init; C/D: col=lane&31, row=(reg&3)+8(reg>>2)+4*l5) ----
    f32x16 accQ[2], accK[2], accV[2];
    {
        const int c0 = h * 64 + cg * 32 + l31;
        const float q0 = bq[c0], k0 = bk[c0], v0 = bv[c0];
        #pragma unroll
        for (int i = 0; i < 16; ++i) {
            accQ[0][i] = q0; accQ[1][i] = q0;
            accK[0][i] = k0; accK[1][i] = k0;
            accV[0][i] = v0; accV[1][i] = v0;
        }
    }

    K1_STAGE(0, 0);

    #pragma unroll 2
    for (int kt = 0; kt < NK1; ++kt) {
        const int cur = kt & 1;
        if (kt + 1 < NK1) {
            K1_STAGE(cur ^ 1, kt + 1);
            if (cnt == 5) asm volatile("s_waitcnt vmcnt(5)" ::: "memory");
            else          asm volatile("s_waitcnt vmcnt(4)" ::: "memory");
        } else {
            asm volatile("s_waitcnt vmcnt(0)" ::: "memory");
        }
        SCB();
        SBAR();                            // stage(kt) visible to all

        const char* bp = smem + cur * 18432;
        const int boff = 8192 + cg * 1024 + lane * 16;
        const f16x8 Bqh = *(const f16x8*)(bp + boff);
        const f16x8 Bql = *(const f16x8*)(bp + boff + 2048);
        const f16x8 Bkh = *(const f16x8*)(bp + boff + 4096);
        const f16x8 Bkl = *(const f16x8*)(bp + boff + 6144);
        const f16x8 Bvh = *(const f16x8*)(bp + boff + 8192);
        f16x8 Ah[2], Al[2];
        #pragma unroll
        for (int rf = 0; rf < 2; ++rf) {
            const int t = rg * 2 + rf;
            Ah[rf] = *(const f16x8*)(bp + (t * 2 + 0) * 1024 + lane * 16);
            Al[rf] = *(const f16x8*)(bp + (t * 2 + 1) * 1024 + lane * 16);
        }
        __builtin_amdgcn_s_setprio(1);
        accQ[0] = MFMA32(Ah[0], Bqh, accQ[0]);
        accQ[1] = MFMA32(Ah[1], Bqh, accQ[1]);
        accK[0] = MFMA32(Ah[0], Bkh, accK[0]);
        accK[1] = MFMA32(Ah[1], Bkh, accK[1]);
        accV[0] = MFMA32(Ah[0], Bvh, accV[0]);
        accV[1] = MFMA32(Ah[1], Bvh, accV[1]);
        accQ[0] = MFMA32(Ah[0], Bql, accQ[0]);
        accQ[1] = MFMA32(Ah[1], Bql, accQ[1]);
        accK[0] = MFMA32(Ah[0], Bkl, accK[0]);
        accK[1] = MFMA32(Ah[1], Bkl, accK[1]);
        accQ[0] = MFMA32(Al[0], Bqh, accQ[0]);
        accQ[1] = MFMA32(Al[1], Bqh, accQ[1]);
        accK[0] = MFMA32(Al[0], Bkh, accK[0]);
        accK[1] = MFMA32(Al[1], Bkh, accK[1]);
        __builtin_amdgcn_s_setprio(0);

        asm volatile("s_waitcnt lgkmcnt(0)" ::: "memory");
        SBAR();                            // buf[cur] free for re-stage
        SCB();
    }

    // ---- attention epilogue: qa/ka dump -> scores -> v overlays qa -> PV ----
    __syncthreads();
    float* qa = (float*)smem;            // [64][68] (17408 B)
    float* ka = qa + 4352;               // [64][68]
    float* va = qa;                      // overlays qa after scores consumed

    const int ar  = tid >> 2;            // 0..63 = t*16 + jj
    const int t_  = ar >> 4;
    const int jj  = ar & 15;
    const int sub = tid & 3;

    #pragma unroll
    for (int hh = 0; hh < 2; ++hh) {
        // dump q,k for token-half hh
        #pragma unroll
        for (int rf = 0; rf < 2; ++rf) {
            const int t = rg * 2 + rf;
            #pragma unroll
            for (int rr = 0; rr < 8; ++rr) {
                const int reg = hh * 8 + rr;
                const int j2  = (rr & 3) + 8 * (rr >> 2) + 4 * l5;   // 0..15
                const int idx = (t * 16 + j2) * 68 + cg * 32 + l31;
                qa[idx] = accQ[rf][reg];
                ka[idx] = accK[rf][reg];
            }
        }
        __syncthreads();

        const float* qp = qa + ar * 68 + sub * 16;
        const float4 q0 = *(const float4*)(qp);
        const float4 q1 = *(const float4*)(qp + 4);
        const float4 q2 = *(const float4*)(qp + 8);
        const float4 q3 = *(const float4*)(qp + 12);
        float sc[4];
        #pragma unroll
        for (int ss = 0; ss < 4; ++ss) {
            const float* kp = ka + (ss * 16 + jj) * 68 + sub * 16;
            const float4 k0 = *(const float4*)(kp);
            const float4 k1 = *(const float4*)(kp + 4);
            const float4 k2 = *(const float4*)(kp + 8);
            const float4 k3 = *(const float4*)(kp + 12);
            float p = q0.x*k0.x + q0.y*k0.y + q0.z*k0.z + q0.w*k0.w
                    + q1.x*k1.x + q1.y*k1.y + q1.z*k1.z + q1.w*k1.w
                    + q2.x*k2.x + q2.y*k2.y + q2.z*k2.z + q2.w*k2.w
                    + q3.x*k3.x + q3.y*k3.y + q3.z*k3.z + q3.w*k3.w;
            p += __shfl_xor(p, 1);
            p += __shfl_xor(p, 2);
            sc[ss] = p;      // spike <=> (dot/8)/2 >= 1 <=> dot >= 16 (exact)
        }
        __syncthreads();     // all score reads of qa done; safe to overlay v

        #pragma unroll
        for (int rf = 0; rf < 2; ++rf) {
            const int t = rg * 2 + rf;
            #pragma unroll
            for (int rr = 0; rr < 8; ++rr) {
                const int reg = hh * 8 + rr;
                const int j2  = (rr & 3) + 8 * (rr >> 2) + 4 * l5;
                va[(t * 16 + j2) * 68 + cg * 32 + l31] = accV[rf][reg];
            }
        }
        __syncthreads();

        float o[16];
        #pragma unroll
        for (int d = 0; d < 16; ++d) o[d] = 0.f;
        #pragma unroll
        for (int ss = 0; ss < 4; ++ss) {
            if (sc[ss] >= 16.0f) {
                const float* vp = va + (ss * 16 + jj) * 68 + sub * 16;
                const float4 v0 = *(const float4*)(vp);
                const float4 v1 = *(const float4*)(vp + 4);
                const float4 v2 = *(const float4*)(vp + 8);
                const float4 v3 = *(const float4*)(vp + 12);
                o[0]+=v0.x; o[1]+=v0.y; o[2]+=v0.z;  o[3]+=v0.w;
                o[4]+=v1.x; o[5]+=v1.y; o[6]+=v1.z;  o[7]+=v1.w;
                o[8]+=v2.x; o[9]+=v2.y; o[10]+=v2.z; o[11]+=v2.w;
                o[12]+=v3.x;o[13]+=v3.y;o[14]+=v3.z; o[15]+=v3.w;
            }
        }
        // store act (fp16, 16-frag blocked layout for k2)
        f16x8 o0, o1;
        #pragma unroll
        for (int d = 0; d < 8; ++d) { o0[d] = (half_t)o[d]; o1[d] = (half_t)o[d + 8]; }
        const int grow = t_ * 1024 + (p0 >> 4) + hh;
        const int colb = h * 64 + sub * 16;
        const size_t cbase = ((size_t)(grow * 16 + (colb >> 5))) << 9;
        const int c0 = (colb >> 3) & 3;
        *(f16x8*)(acth + cbase + (size_t)((c0       * 16 + jj) << 3)) = o0;
        *(f16x8*)(acth + cbase + (size_t)(((c0 + 1) * 16 + jj) << 3)) = o1;
        __syncthreads();
    }
#undef K1_STAGE
}

// ---------------------------------------------------------------------------
// k2: out = act @ Wo^T + bo, fp16 16x16x32 MFMA, LDS-staged counted-vmcnt
// (round-4 proven) + setprio around the MFMA cluster.
// ---------------------------------------------------------------------------
__global__ __launch_bounds__(256, 4)
void k2_gemm(const half_t* __restrict__ acth, const half_t* __restrict__ oh,
             const float* __restrict__ bo, float* __restrict__ out)
{
    __shared__ __align__(16) char smem[32768];

    const int tid  = threadIdx.x;
    const int lane = tid & 63;
    const int wv   = tid >> 6;
    const int wr   = wv >> 1, wc = wv & 1;
    const int l15  = lane & 15, l4 = lane >> 4;
    const int bn   = (blockIdx.x & 3) * 128;
    const int bm   = (blockIdx.x >> 2) * 128;

    const half_t* gb[4]; int lo_[4];
    #pragma unroll
    for (int ii = 0; ii < 4; ++ii) {
        const int i = wv * 4 + ii;
        if (i < 8) {
            const int grow = (bm >> 4) + i;
            gb[ii] = acth + ((size_t)grow << 13) + lane * 8;
            lo_[ii] = i * 1024;
        } else {
            const int fb = i - 8;
            const int grow = (bn >> 4) + fb;
            gb[ii] = oh + ((size_t)grow << 13) + lane * 8;
            lo_[ii] = 8192 + fb * 1024;
        }
    }

#define K2_STAGE(buf, kt) do {                                                  \
    _Pragma("unroll")                                                           \
    for (int ii = 0; ii < 4; ++ii)                                              \
        __builtin_amdgcn_global_load_lds(                                       \
            (const __attribute__((address_space(1))) void*)(gb[ii] + (size_t)(kt) * 512), \
            (__attribute__((address_space(3))) void*)(smem + (buf) * 16384 + lo_[ii]),    \
            16, 0, 0);                                                          \
    } while (0)

    f32x4 acc[4][4];
    #pragma unroll
    for (int rf = 0; rf < 4; ++rf)
        #pragma unroll
        for (int cf = 0; cf < 4; ++cf) acc[rf][cf] = f32x4{0.f, 0.f, 0.f, 0.f};

    K2_STAGE(0, 0);

    #pragma unroll
    for (int kt = 0; kt < NK2; ++kt) {
        const int cur = kt & 1;
        if (kt + 1 < NK2) {
            K2_STAGE(cur ^ 1, kt + 1);
            asm volatile("s_waitcnt vmcnt(4)" ::: "memory");
        } else {
            asm volatile("s_waitcnt vmcnt(0)" ::: "memory");
        }
        SCB();
        SBAR();

        const char* bp = smem + cur * 16384;
        f16x8 B[4];
        #pragma unroll
        for (int cf = 0; cf < 4; ++cf)
            B[cf] = *(const f16x8*)(bp + 8192 + (wc * 4 + cf) * 1024 + lane * 16);
        f16x8 A[4];
        #pragma unroll
        for (int rf = 0; rf < 4; ++rf)
            A[rf] = *(const f16x8*)(bp + (wr * 4 + rf) * 1024 + lane * 16);
        asm volatile("s_waitcnt lgkmcnt(0)" ::: "memory");
        SCB();
        __builtin_amdgcn_s_setprio(1);
        #pragma unroll
        for (int rf = 0; rf < 4; ++rf)
            #pragma unroll
            for (int cf = 0; cf < 4; ++cf)
                acc[rf][cf] = MFMA16(A[rf], B[cf], acc[rf][cf]);
        __builtin_amdgcn_s_setprio(0);
        SBAR();
        SCB();
    }

    float bo4[4];
    #pragma unroll
    for (int cf = 0; cf < 4; ++cf) bo4[cf] = bo[bn + (wc * 4 + cf) * 16 + l15];

    #pragma unroll
    for (int rf = 0; rf < 4; ++rf) {
        const int row0 = bm + (wr * 4 + rf) * 16 + l4 * 4;
        #pragma unroll
        for (int cf = 0; cf < 4; ++cf) {
            const int col = bn + (wc * 4 + cf) * 16 + l15;
            #pragma unroll
            for (int r = 0; r < 4; ++r)
                out[(size_t)(row0 + r) * CCC + col] = acc[rf][cf][r] + bo4[cf];
        }
    }
#undef K2_STAGE
}

// ---------------------------------------------------------------------------
extern "C" void kernel_launch(void* const* d_in, const int* in_sizes, int n_in,
                              void* d_out, int out_size, void* d_ws, size_t ws_size,
                              hipStream_t stream)
{
    const float* x  = (const float*)d_in[0];
    const float* Wq = (const float*)d_in[1];
    const float* bq = (const float*)d_in[2];
    const float* Wk = (const float*)d_in[3];
    const float* bk = (const float*)d_in[4];
    const float* Wv = (const float*)d_in[5];
    const float* bv = (const float*)d_in[6];
    const float* Wo = (const float*)d_in[7];
    const float* bo = (const float*)d_in[8];

    half_t* ws   = (half_t*)d_ws;
    half_t* acth = ws + ACT_OFF;
    float*  out  = (float*)d_out;

    hipLaunchKernelGGL(k0_split, dim3(16896), dim3(256), 0, stream,
                       x, Wq, Wk, Wv, Wo, ws);
    hipLaunchKernelGGL(k1_mfma, dim3(4096), dim3(256), 0, stream,
                       ws, bq, bk, bv, acth);
    hipLaunchKernelGGL(k2_gemm, dim3(2048), dim3(256), 0, stream,
                       acth, ws + W_OFF + 5*WPL, bo, out);
}

// Round 12
// 374.427 us; speedup vs baseline: 5.1526x; 5.1526x over previous
//
#include <hip/hip_runtime.h>

#define PTOT  16384
#define CCC   512
#define HHH   8
#define NK1   32                 /* k1: 512/16 k-steps */
#define NK2   16                 /* k2: 512/32 k-steps */

typedef __attribute__((ext_vector_type(4)))  float f32x4;
typedef __attribute__((ext_vector_type(16))) float f32x16;
typedef _Float16 half_t;
typedef __attribute__((ext_vector_type(8))) _Float16 f16x8;

#define MFMA16(a,b,c) __builtin_amdgcn_mfma_f32_16x16x32_f16(a,b,c,0,0,0)
#define MFMA32(a,b,c) __builtin_amdgcn_mfma_f32_32x32x16_f16(a,b,c,0,0,0)

// ---- ws layout (half elements): W planes 0..4 = qh,ql,kh,kl,vh (32-frag),
// plane 5 = Wo (16-frag), act at 6*WPL. x is NOT pre-split anymore.
#define WPL      ((size_t)262144)
#define ACT_OFF  ((size_t)(6 * 262144))

#define SCB()   __builtin_amdgcn_sched_barrier(0)
#define SBAR()  __builtin_amdgcn_s_barrier()

// 16-row frag layout (act plane + Wo plane; k2 consumes via 16x16x32 MFMA)
__device__ __forceinline__ size_t blk_off16(int row, int col) {
    return ((size_t)((row >> 4) * 16 + (col >> 5)) << 9)
         + (size_t)(((((col >> 3) & 3) * 16) + (row & 15)) << 3) + (col & 7);
}

// ---------------------------------------------------------------------------
// k0: split W matrices only (x handled in k1). 512 blocks x 256 thr.
// ---------------------------------------------------------------------------
__global__ void k0_split(const float* __restrict__ Wq, const float* __restrict__ Wk,
                         const float* __restrict__ Wv, const float* __restrict__ Wo,
                         half_t* __restrict__ ws)
{
    const int u = blockIdx.x * 256 + threadIdx.x;   // 131072 threads
    const int mat = u >> 15, r = u & 32767;
    if (mat < 3) {                                  // ---- Wq/Wk/Wv, 32-layout ----
        const float* src = (mat == 0) ? Wq : (mat == 1) ? Wk : Wv;
        const int f = r >> 6, lane6 = r & 63;
        const int grow32 = f >> 5, ktc = f & 31;
        const int row = grow32 * 32 + (lane6 & 31);
        const int k   = ktc * 16 + (lane6 >> 5) * 8;
        const float4 a = *(const float4*)(src + (size_t)row * CCC + k);
        const float4 b = *(const float4*)(src + (size_t)row * CCC + k + 4);
        const float e[8] = {a.x, a.y, a.z, a.w, b.x, b.y, b.z, b.w};
        f16x8 vh8, vl8;
        #pragma unroll
        for (int d = 0; d < 8; ++d) {
            const half_t hi = (half_t)e[d];
            vh8[d] = hi; vl8[d] = (half_t)(e[d] - (float)hi);
        }
        const size_t off = ((size_t)f << 9) + lane6 * 8;
        half_t* dh = ws + (size_t)(mat * 2) * WPL;
        *(f16x8*)(dh + off) = vh8;
        if (mat < 2) *(f16x8*)(dh + WPL + off) = vl8;   // lo plane for q,k only
        return;
    }
    // ---- Wo, 16-layout ----
    const int gr = r >> 10, v = r & 1023;
    const int ktc = v >> 6, chunk = (v >> 4) & 3, i = v & 15;
    const int row = gr * 16 + i, col = ktc * 32 + chunk * 8;
    const float4 a = *(const float4*)(Wo + (size_t)row * CCC + col);
    const float4 b = *(const float4*)(Wo + (size_t)row * CCC + col + 4);
    const float e[8] = {a.x, a.y, a.z, a.w, b.x, b.y, b.z, b.w};
    f16x8 vh8;
    #pragma unroll
    for (int d = 0; d < 8; ++d) vh8[d] = (half_t)e[d];
    *(f16x8*)(ws + 5 * WPL + blk_off16(row, col)) = vh8;
}

// ---------------------------------------------------------------------------
// k1: QKV projection via fp16x2 32x32x16 MFMA (Q:3,K:3,V:1) + spiking attn.
// r5-proven pipeline (counted vmcnt, 2 barriers/kt, 3 blocks/CU). NEW: x is
// gathered fp32 straight from its original layout via per-lane global_load_lds
// (no pre-split pass); h/l fp16 split happens in registers after ds_read.
// ---------------------------------------------------------------------------
__global__ __launch_bounds__(256, 3)
void k1_mfma(const float* __restrict__ x, const half_t* __restrict__ ws,
             const float* __restrict__ bq, const float* __restrict__ bk,
             const float* __restrict__ bv,
             half_t* __restrict__ acth)
{
    __shared__ __align__(16) char smem[52224];

    const int tid  = threadIdx.x;
    const int lane = tid & 63;
    const int wv   = tid >> 6;
    const int rg   = wv >> 1;        // row half: 64 rows
    const int cg   = wv & 1;         // col half: 32 cols
    const int l31  = lane & 31;
    const int l5   = lane >> 5;

    const int xcd  = blockIdx.x & 7;
    const int rest = blockIdx.x >> 3;
    const int h    = rest & 7;
    const int tg   = rest >> 3;
    const int p0   = (tg * 8 + xcd) * 32;

    // ---- staging issue list: 18 units/kt/block (8 x-gather + 10 W), [5,5,4,4] ----
    // x unit (t,uh): lane l -> x[t*PTOT + p0 + (l&31)][kt*16 + (l>>5)*8 + uh*4]
    //   LDS slot (t*2+uh)*1024 + l*16  (frag j=0..3 in uh=0, j=4..7 in uh=1)
    const int cnt  = (wv < 2) ? 5 : 4;
    const int base = (wv < 2) ? wv * 5 : 2 + wv * 4;
    const char* gsrc[5]; int gstr[5]; int lo_[5];
    #pragma unroll
    for (int ii = 0; ii < 5; ++ii) {
        const int i = base + ii;
        if (i < 8) {
            const int t = i >> 1, uh = i & 1;
            gsrc[ii] = (const char*)(x + ((size_t)t * PTOT + p0 + (lane & 31)) * CCC
                                       + (lane >> 5) * 8 + uh * 4);
            gstr[ii] = 64;                  // 16 fp32 per kt
            lo_[ii]  = i * 1024;
        } else {
            const int s = i - 8, plw = s >> 1, cb = s & 1;
            gsrc[ii] = (const char*)(ws + (size_t)plw * WPL
                                        + ((size_t)(h * 2 + cb) << 14) + lane * 8);
            gstr[ii] = 1024;                // 512 halves per kt
            lo_[ii]  = 8192 + s * 1024;
        }
    }

#define K1_STAGE(buf, kt) do {                                                  \
    _Pragma("unroll")                                                           \
    for (int ii = 0; ii < 5; ++ii)                                              \
        if (ii < cnt)                                                           \
            __builtin_amdgcn_global_load_lds(                                   \
                (const __attribute__((address_space(1))) void*)(gsrc[ii] + (size_t)(kt) * gstr[ii]), \
                (__attribute__((address_space(3))) void*)(smem + (buf) * 18432 + lo_[ii]),           \
                16, 0, 0);                                                      \
    } while (0)

    // ---- accumulators (bias init; C/D: col=lane&31, row=(reg&3)+8(reg>>2)+4*l5) ----
    f32x16 accQ[2], accK[2], accV[2];
    {
        const int c0 = h * 64 + cg * 32 + l31;
        const float q0 = bq[c0], k0 = bk[c0], v0 = bv[c0];
        #pragma unroll
        for (int i = 0; i < 16; ++i) {
            accQ[0][i] = q0; accQ[1][i] = q0;
            accK[0][i] = k0; accK[1][i] = k0;
            accV[0][i] = v0; accV[1][i] = v0;
        }
    }

    K1_STAGE(0, 0);

    #pragma unroll 2
    for (int kt = 0; kt < NK1; ++kt) {
        const int cur = kt & 1;
        if (kt + 1 < NK1) {
            K1_STAGE(cur ^ 1, kt + 1);
            if (cnt == 5) asm volatile("s_waitcnt vmcnt(5)" ::: "memory");
            else          asm volatile("s_waitcnt vmcnt(4)" ::: "memory");
        } else {
            asm volatile("s_waitcnt vmcnt(0)" ::: "memory");
        }
        SCB();
        SBAR();                            // stage(kt) visible to all

        const char* bp = smem + cur * 18432;
        const int boff = 8192 + cg * 1024 + lane * 16;
        const f16x8 Bqh = *(const f16x8*)(bp + boff);
        const f16x8 Bql = *(const f16x8*)(bp + boff + 2048);
        const f16x8 Bkh = *(const f16x8*)(bp + boff + 4096);
        const f16x8 Bkl = *(const f16x8*)(bp + boff + 6144);
        const f16x8 Bvh = *(const f16x8*)(bp + boff + 8192);

        // A frags: read fp32 x, split h/l in registers
        f16x8 Ah[2], Al[2];
        #pragma unroll
        for (int rf = 0; rf < 2; ++rf) {
            const int t = rg * 2 + rf;
            const f32x4 alo = *(const f32x4*)(bp + (t * 2 + 0) * 1024 + lane * 16);
            const f32x4 ahi = *(const f32x4*)(bp + (t * 2 + 1) * 1024 + lane * 16);
            const float e[8] = {alo[0], alo[1], alo[2], alo[3],
                                ahi[0], ahi[1], ahi[2], ahi[3]};
            #pragma unroll
            for (int d = 0; d < 8; ++d) {
                const half_t hi8 = (half_t)e[d];
                Ah[rf][d] = hi8;
                Al[rf][d] = (half_t)(e[d] - (float)hi8);
            }
        }

        __builtin_amdgcn_s_setprio(1);
        accQ[0] = MFMA32(Ah[0], Bqh, accQ[0]);
        accQ[1] = MFMA32(Ah[1], Bqh, accQ[1]);
        accK[0] = MFMA32(Ah[0], Bkh, accK[0]);
        accK[1] = MFMA32(Ah[1], Bkh, accK[1]);
        accV[0] = MFMA32(Ah[0], Bvh, accV[0]);
        accV[1] = MFMA32(Ah[1], Bvh, accV[1]);
        accQ[0] = MFMA32(Ah[0], Bql, accQ[0]);
        accQ[1] = MFMA32(Ah[1], Bql, accQ[1]);
        accK[0] = MFMA32(Ah[0], Bkl, accK[0]);
        accK[1] = MFMA32(Ah[1], Bkl, accK[1]);
        accQ[0] = MFMA32(Al[0], Bqh, accQ[0]);
        accQ[1] = MFMA32(Al[1], Bqh, accQ[1]);
        accK[0] = MFMA32(Al[0], Bkh, accK[0]);
        accK[1] = MFMA32(Al[1], Bkh, accK[1]);
        __builtin_amdgcn_s_setprio(0);

        asm volatile("s_waitcnt lgkmcnt(0)" ::: "memory");
        SBAR();                            // buf[cur] free for re-stage
        SCB();
    }

    // ---- attention epilogue (two 16-token passes; LDS overlay) ----
    __syncthreads();
    float* qa = (float*)smem;            // [64][68]
    float* ka = qa + 4352;
    float* va = qa + 8704;

    const int ar  = tid >> 2;            // 0..63 = t*16 + jj
    const int t_  = ar >> 4;
    const int jj  = ar & 15;
    const int sub = tid & 3;

    #pragma unroll
    for (int hh = 0; hh < 2; ++hh) {
        #pragma unroll
        for (int rf = 0; rf < 2; ++rf) {
            const int t = rg * 2 + rf;
            #pragma unroll
            for (int rr = 0; rr < 8; ++rr) {
                const int reg = hh * 8 + rr;
                const int j2  = (rr & 3) + 8 * (rr >> 2) + 4 * l5;   // 0..15
                const int idx = (t * 16 + j2) * 68 + cg * 32 + l31;
                qa[idx] = accQ[rf][reg];
                ka[idx] = accK[rf][reg];
                va[idx] = accV[rf][reg];
            }
        }
        __syncthreads();

        const float* qp = qa + ar * 68 + sub * 16;
        const float4 q0 = *(const float4*)(qp);
        const float4 q1 = *(const float4*)(qp + 4);
        const float4 q2 = *(const float4*)(qp + 8);
        const float4 q3 = *(const float4*)(qp + 12);
        float sc[4];
        #pragma unroll
        for (int ss = 0; ss < 4; ++ss) {
            const float* kp = ka + (ss * 16 + jj) * 68 + sub * 16;
            const float4 k0 = *(const float4*)(kp);
            const float4 k1 = *(const float4*)(kp + 4);
            const float4 k2 = *(const float4*)(kp + 8);
            const float4 k3 = *(const float4*)(kp + 12);
            float p = q0.x*k0.x + q0.y*k0.y + q0.z*k0.z + q0.w*k0.w
                    + q1.x*k1.x + q1.y*k1.y + q1.z*k1.z + q1.w*k1.w
                    + q2.x*k2.x + q2.y*k2.y + q2.z*k2.z + q2.w*k2.w
                    + q3.x*k3.x + q3.y*k3.y + q3.z*k3.z + q3.w*k3.w;
            p += __shfl_xor(p, 1);
            p += __shfl_xor(p, 2);
            sc[ss] = p;      // spike <=> (dot/8)/2 >= 1 <=> dot >= 16 (exact)
        }
        float o[16];
        #pragma unroll
        for (int d = 0; d < 16; ++d) o[d] = 0.f;
        #pragma unroll
        for (int ss = 0; ss < 4; ++ss) {
            if (sc[ss] >= 16.0f) {
                const float* vp = va + (ss * 16 + jj) * 68 + sub * 16;
                const float4 v0 = *(const float4*)(vp);
                const float4 v1 = *(const float4*)(vp + 4);
                const float4 v2 = *(const float4*)(vp + 8);
                const float4 v3 = *(const float4*)(vp + 12);
                o[0]+=v0.x; o[1]+=v0.y; o[2]+=v0.z;  o[3]+=v0.w;
                o[4]+=v1.x; o[5]+=v1.y; o[6]+=v1.z;  o[7]+=v1.w;
                o[8]+=v2.x; o[9]+=v2.y; o[10]+=v2.z; o[11]+=v2.w;
                o[12]+=v3.x;o[13]+=v3.y;o[14]+=v3.z; o[15]+=v3.w;
            }
        }
        // store act (fp16, 16-frag blocked layout for k2)
        f16x8 o0, o1;
        #pragma unroll
        for (int d = 0; d < 8; ++d) { o0[d] = (half_t)o[d]; o1[d] = (half_t)o[d + 8]; }
        const int grow = t_ * 1024 + (p0 >> 4) + hh;
        const int colb = h * 64 + sub * 16;
        const size_t cbase = ((size_t)(grow * 16 + (colb >> 5))) << 9;
        const int c0 = (colb >> 3) & 3;
        *(f16x8*)(acth + cbase + (size_t)((c0       * 16 + jj) << 3)) = o0;
        *(f16x8*)(acth + cbase + (size_t)(((c0 + 1) * 16 + jj) << 3)) = o1;
        __syncthreads();
    }
#undef K1_STAGE
}

// ---------------------------------------------------------------------------
// k2: out = act @ Wo^T + bo, fp16 16x16x32 MFMA, LDS-staged counted-vmcnt
// (round-4/7 proven) + setprio around the MFMA cluster.
// ---------------------------------------------------------------------------
__global__ __launch_bounds__(256, 4)
void k2_gemm(const half_t* __restrict__ acth, const half_t* __restrict__ oh,
             const float* __restrict__ bo, float* __restrict__ out)
{
    __shared__ __align__(16) char smem[32768];

    const int tid  = threadIdx.x;
    const int lane = tid & 63;
    const int wv   = tid >> 6;
    const int wr   = wv >> 1, wc = wv & 1;
    const int l15  = lane & 15, l4 = lane >> 4;
    const int bn   = (blockIdx.x & 3) * 128;
    const int bm   = (blockIdx.x >> 2) * 128;

    const half_t* gb[4]; int lo_[4];
    #pragma unroll
    for (int ii = 0; ii < 4; ++ii) {
        const int i = wv * 4 + ii;
        if (i < 8) {
            const int grow = (bm >> 4) + i;
            gb[ii] = acth + ((size_t)grow << 13) + lane * 8;
            lo_[ii] = i * 1024;
        } else {
            const int fb = i - 8;
            const int grow = (bn >> 4) + fb;
            gb[ii] = oh + ((size_t)grow << 13) + lane * 8;
            lo_[ii] = 8192 + fb * 1024;
        }
    }

#define K2_STAGE(buf, kt) do {                                                  \
    _Pragma("unroll")                                                           \
    for (int ii = 0; ii < 4; ++ii)                                              \
        __builtin_amdgcn_global_load_lds(                                       \
            (const __attribute__((address_space(1))) void*)(gb[ii] + (size_t)(kt) * 512), \
            (__attribute__((address_space(3))) void*)(smem + (buf) * 16384 + lo_[ii]),    \
            16, 0, 0);                                                          \
    } while (0)

    f32x4 acc[4][4];
    #pragma unroll
    for (int rf = 0; rf < 4; ++rf)
        #pragma unroll
        for (int cf = 0; cf < 4; ++cf) acc[rf][cf] = f32x4{0.f, 0.f, 0.f, 0.f};

    K2_STAGE(0, 0);

    #pragma unroll
    for (int kt = 0; kt < NK2; ++kt) {
        const int cur = kt & 1;
        if (kt + 1 < NK2) {
            K2_STAGE(cur ^ 1, kt + 1);
            asm volatile("s_waitcnt vmcnt(4)" ::: "memory");
        } else {
            asm volatile("s_waitcnt vmcnt(0)" ::: "memory");
        }
        SCB();
        SBAR();

        const char* bp = smem + cur * 16384;
        f16x8 B[4];
        #pragma unroll
        for (int cf = 0; cf < 4; ++cf)
            B[cf] = *(const f16x8*)(bp + 8192 + (wc * 4 + cf) * 1024 + lane * 16);
        f16x8 A[4];
        #pragma unroll
        for (int rf = 0; rf < 4; ++rf)
            A[rf] = *(const f16x8*)(bp + (wr * 4 + rf) * 1024 + lane * 16);
        asm volatile("s_waitcnt lgkmcnt(0)" ::: "memory");
        SCB();
        __builtin_amdgcn_s_setprio(1);
        #pragma unroll
        for (int rf = 0; rf < 4; ++rf)
            #pragma unroll
            for (int cf = 0; cf < 4; ++cf)
                acc[rf][cf] = MFMA16(A[rf], B[cf], acc[rf][cf]);
        __builtin_amdgcn_s_setprio(0);
        SBAR();
        SCB();
    }

    float bo4[4];
    #pragma unroll
    for (int cf = 0; cf < 4; ++cf) bo4[cf] = bo[bn + (wc * 4 + cf) * 16 + l15];

    #pragma unroll
    for (int rf = 0; rf < 4; ++rf) {
        const int row0 = bm + (wr * 4 + rf) * 16 + l4 * 4;
        #pragma unroll
        for (int cf = 0; cf < 4; ++cf) {
            const int col = bn + (wc * 4 + cf) * 16 + l15;
            #pragma unroll
            for (int r = 0; r < 4; ++r)
                out[(size_t)(row0 + r) * CCC + col] = acc[rf][cf][r] + bo4[cf];
        }
    }
#undef K2_STAGE
}

// ---------------------------------------------------------------------------
extern "C" void kernel_launch(void* const* d_in, const int* in_sizes, int n_in,
                              void* d_out, int out_size, void* d_ws, size_t ws_size,
                              hipStream_t stream)
{
    const float* x  = (const float*)d_in[0];
    const float* Wq = (const float*)d_in[1];
    const float* bq = (const float*)d_in[2];
    const float* Wk = (const float*)d_in[3];
    const float* bk = (const float*)d_in[4];
    const float* Wv = (const float*)d_in[5];
    const float* bv = (const float*)d_in[6];
    const float* Wo = (const float*)d_in[7];
    const float* bo = (const float*)d_in[8];

    half_t* ws   = (half_t*)d_ws;
    half_t* acth = ws + ACT_OFF;
    float*  out  = (float*)d_out;

    hipLaunchKernelGGL(k0_split, dim3(512), dim3(256), 0, stream,
                       Wq, Wk, Wv, Wo, ws);
    hipLaunchKernelGGL(k1_mfma, dim3(4096), dim3(256), 0, stream,
                       x, ws, bq, bk, bv, acth);
    hipLaunchKernelGGL(k2_gemm, dim3(2048), dim3(256), 0, stream,
                       acth, ws + 5 * WPL, bo, out);
}